// Round 2
// baseline (703.975 us; speedup 1.0000x reference)
//
#include <hip/hip_runtime.h>
#include <hip/hip_bf16.h>
#include <math.h>

// Problem constants
#define NB 32     // batch
#define NN 128    // sequence (= 16 x 8)
#define ND 512    // model dim
#define NDI 1024  // inner dim
#define NDS 16    // state dim
#define NDR 32    // dt rank

typedef __attribute__((ext_vector_type(8))) __bf16 bf16x8;
typedef __attribute__((ext_vector_type(4))) float f32x4;

typedef __attribute__((address_space(3))) void lds_void;
typedef const __attribute__((address_space(1))) void glob_void;

__device__ __forceinline__ void gload16(const void* g, void* l) {
    __builtin_amdgcn_global_load_lds((glob_void*)g, (lds_void*)l, 16, 0, 0);
}

__device__ __forceinline__ float softplusf(float x) {
    if (x > 20.f) return x;
    if (x < -20.f) return expf(x);
    return log1pf(expf(x));
}

__device__ __forceinline__ unsigned short f2bf(float x) {
    __hip_bfloat16 h = __float2bfloat16(x);
    return *(unsigned short*)&h;
}

// ---------------------------------------------------------------------------
// K0: fp32 -> bf16 conversion (RTNE), vectorized float4 -> ushort4.
// ---------------------------------------------------------------------------
__global__ __launch_bounds__(256) void k_cvt(
    const float* __restrict__ s, unsigned short* __restrict__ d, int n4)
{
    for (int i = blockIdx.x * 256 + threadIdx.x; i < n4; i += gridDim.x * 256) {
        const float4 v = ((const float4*)s)[i];
        ushort4 o;
        o.x = f2bf(v.x); o.y = f2bf(v.y); o.z = f2bf(v.z); o.w = f2bf(v.w);
        ((ushort4*)d)[i] = o;
    }
}

// ---------------------------------------------------------------------------
// K1: in_proj as bf16 MFMA GEMM (m97 structure).
// A: [3][4096][512] bf16 (row-major, K contiguous)
// B: [3][2048][512] bf16 (row-major, K contiguous)  -> NT GEMM
// C: e<1024 -> xb (fp32), e>=1024 -> zbf (bf16). Tile 128x128, BK=32.
// ---------------------------------------------------------------------------
__global__ __launch_bounds__(256) void k_gemm_inproj(
    const unsigned short* __restrict__ Abf,
    const unsigned short* __restrict__ Wbf,
    float* __restrict__ xb, __hip_bfloat16* __restrict__ zbf)
{
    const int m = blockIdx.z;
    const int row0 = blockIdx.x * 128;
    const int col0 = blockIdx.y * 128;
    const unsigned short* __restrict__ A = Abf + (size_t)m * 4096 * 512;
    const unsigned short* __restrict__ Bw = Wbf + (size_t)m * 2048 * 512;
    const int K = 512;
    const int NT = K / 32;

    const int tid = threadIdx.x;
    const int lane = tid & 63;
    const int wave = tid >> 6;
    const int wr = wave >> 1, wc = wave & 1;
    const int lr16 = lane & 15;
    const int kk8 = (lane >> 4) << 3;

    __shared__ __align__(16) short sA[2][128 * 32];
    __shared__ __align__(16) short sB[2][128 * 32];

    f32x4 acc[4][4];
    #pragma unroll
    for (int i = 0; i < 4; ++i)
        #pragma unroll
        for (int j = 0; j < 4; ++j)
            acc[i][j] = (f32x4){0.f, 0.f, 0.f, 0.f};

    // stage tile t into buffer buf (A: 128x32 bf16 = 8 KB, 2 rounds of 256x16B)
    #define STAGE(buf, t)                                                        \
        {                                                                        \
            const int k0 = (t) * 32;                                             \
            _Pragma("unroll")                                                    \
            for (int i = 0; i < 2; ++i) {                                        \
                const int c = i * 256 + tid;                                     \
                const int rowc = c >> 2;                                         \
                const int kc = (c & 3) << 3;                                     \
                gload16(A + (size_t)(row0 + rowc) * K + k0 + kc,                 \
                        &sA[buf][rowc * 32 + kc]);                               \
                gload16(Bw + (size_t)(col0 + rowc) * K + k0 + kc,                \
                        &sB[buf][rowc * 32 + kc]);                               \
            }                                                                    \
        }

    #define COMPUTE(buf)                                                         \
        {                                                                        \
            bf16x8 af[4], bfr[4];                                                \
            _Pragma("unroll")                                                    \
            for (int i = 0; i < 4; ++i) {                                        \
                af[i]  = *(const bf16x8*)&sA[buf][(wr * 64 + i * 16 + lr16) * 32 + kk8]; \
                bfr[i] = *(const bf16x8*)&sB[buf][(wc * 64 + i * 16 + lr16) * 32 + kk8]; \
            }                                                                    \
            _Pragma("unroll")                                                    \
            for (int i = 0; i < 4; ++i)                                          \
                _Pragma("unroll")                                                \
                for (int j = 0; j < 4; ++j)                                      \
                    acc[i][j] = __builtin_amdgcn_mfma_f32_16x16x32_bf16(         \
                        af[i], bfr[j], acc[i][j], 0, 0, 0);                      \
        }

    STAGE(0, 0);
    __syncthreads();
    int cur = 0;
    for (int t = 0; t < NT - 1; ++t) {
        STAGE(cur ^ 1, t + 1);
        COMPUTE(cur);
        __syncthreads();
        cur ^= 1;
    }
    COMPUTE(cur);

    // epilogue: C[row][col], rows = (lane>>4)*4 + r per fragment, col = lane&15
    const bool isX = (col0 < 1024);
    #pragma unroll
    for (int i = 0; i < 4; ++i) {
        const int rb = row0 + wr * 64 + i * 16 + ((lane >> 4) << 2);
        #pragma unroll
        for (int j = 0; j < 4; ++j) {
            const int cc = col0 + wc * 64 + j * 16 + lr16;
            #pragma unroll
            for (int r = 0; r < 4; ++r) {
                const float v = acc[i][j][r];
                const int row = rb + r;
                if (isX)
                    xb[((size_t)m * 4096 + row) * 1024 + cc] = v;
                else
                    zbf[((size_t)m * 4096 + row) * 1024 + (cc - 1024)] =
                        __float2bfloat16(v);
            }
        }
    }
    #undef STAGE
    #undef COMPUTE
}

// ---------------------------------------------------------------------------
// K2: depthwise 3x3 conv (SAME) + bias + BN + SiLU. Spatial 16x8, n = h*8+w.
// ---------------------------------------------------------------------------
__global__ __launch_bounds__(256) void k_conv(
    const float* __restrict__ x, const float* __restrict__ cw,
    const float* __restrict__ cb, const float* __restrict__ gm,
    const float* __restrict__ bt, const float* __restrict__ mn,
    const float* __restrict__ vr, float* __restrict__ out)
{
    const int nIdx = blockIdx.x;       // 0..127
    const int b = blockIdx.y;
    const int m = blockIdx.z;
    const int h = nIdx >> 3, w = nIdx & 7;
    const float* __restrict__ xm = x + ((size_t)(m * NB + b)) * NN * NDI;

    #pragma unroll
    for (int q = 0; q < 4; ++q) {
        const int di = (q << 8) + threadIdx.x;
        const float* __restrict__ wp = cw + ((size_t)(m * NDI + di)) * 9;
        float s = 0.f;
        #pragma unroll
        for (int kh = 0; kh < 3; ++kh) {
            const int hh = h + kh - 1;
            if ((unsigned)hh < 16u) {
                #pragma unroll
                for (int kw = 0; kw < 3; ++kw) {
                    const int ww = w + kw - 1;
                    if ((unsigned)ww < 8u)
                        s = fmaf(xm[(size_t)(hh * 8 + ww) * NDI + di],
                                 wp[kh * 3 + kw], s);
                }
            }
        }
        const int c = m * NDI + di;
        const float scale = gm[c] * rsqrtf(vr[c] + 1e-5f);
        const float y = (s + cb[c] - mn[c]) * scale + bt[c];
        out[((size_t)(m * NB + b) * NN + nIdx) * NDI + di] = y / (1.f + expf(-y));
    }
}

// ---------------------------------------------------------------------------
// K3: xproj (fp32 vector GEMM, only 3.2 GF). xd[s,row,e], e in [0,64).
// ---------------------------------------------------------------------------
__global__ __launch_bounds__(256) void k_xproj(
    const float* __restrict__ xc, const float* __restrict__ xw,
    float* __restrict__ xd)
{
    const int s = blockIdx.z;
    const int m = s % 3;
    const bool rev = s >= 3;
    const float* __restrict__ A = xc + (size_t)m * 4096 * NDI;
    const float* __restrict__ Bw = xw + (size_t)s * 64 * NDI;
    const int row0 = blockIdx.x * 64;
    const int tid = threadIdx.x;
    const int tx = tid & 15, ty = tid >> 4;
    const int lr = tid >> 2;
    const int lk = (tid & 3) << 2;

    __shared__ float As[16][64];
    __shared__ float Bs[16][64];
    float acc[4][4] = {};

    const int arow = row0 + lr;
    const int ab = arow >> 7, at = arow & 127;
    const int srow = ab * NN + (rev ? (NN - 1 - at) : at);

    for (int k0 = 0; k0 < NDI; k0 += 16) {
        const float4 av = *(const float4*)(A + (size_t)srow * NDI + k0 + lk);
        const float4 bv = *(const float4*)(Bw + (size_t)lr * NDI + k0 + lk);
        __syncthreads();
        As[lk + 0][lr] = av.x; As[lk + 1][lr] = av.y;
        As[lk + 2][lr] = av.z; As[lk + 3][lr] = av.w;
        Bs[lk + 0][lr] = bv.x; Bs[lk + 1][lr] = bv.y;
        Bs[lk + 2][lr] = bv.z; Bs[lk + 3][lr] = bv.w;
        __syncthreads();
        #pragma unroll
        for (int kk = 0; kk < 16; ++kk) {
            const float4 a4 = *(const float4*)&As[kk][ty << 2];
            const float4 b4 = *(const float4*)&Bs[kk][tx << 2];
            const float ar[4] = {a4.x, a4.y, a4.z, a4.w};
            const float br[4] = {b4.x, b4.y, b4.z, b4.w};
            #pragma unroll
            for (int i = 0; i < 4; ++i)
                #pragma unroll
                for (int j = 0; j < 4; ++j)
                    acc[i][j] = fmaf(ar[i], br[j], acc[i][j]);
        }
    }
    const int e0 = tx << 2;
    #pragma unroll
    for (int i = 0; i < 4; ++i) {
        const int row = row0 + (ty << 2) + i;
        *(float4*)(xd + ((size_t)s * 4096 + row) * 64 + e0) =
            make_float4(acc[i][0], acc[i][1], acc[i][2], acc[i][3]);
    }
}

// ---------------------------------------------------------------------------
// K4: fused selective scan. One thread per (s,b,d) channel; 128 steps.
// ---------------------------------------------------------------------------
__global__ __launch_bounds__(256) void k_scan(
    const float* __restrict__ xc, const float* __restrict__ xd,
    const float* __restrict__ dtw, const float* __restrict__ dtb,
    const float* __restrict__ alog, const float* __restrict__ Dp,
    float* __restrict__ y6)
{
    const int s = blockIdx.z, b = blockIdx.y;
    const int d = blockIdx.x * 256 + threadIdx.x;
    const int m = s % 3;
    const bool rev = s >= 3;

    __shared__ float xdl[NN * 64];  // 32 KB
    const float* __restrict__ xdp = xd + ((size_t)(s * NB + b)) * NN * 64;
    for (int i = threadIdx.x; i < NN * 64; i += 256) xdl[i] = xdp[i];

    float a[NDS], wdt[NDR], h[NDS];
    const float* __restrict__ ap = alog + ((size_t)s * NDI + d) * NDS;
    #pragma unroll
    for (int j = 0; j < NDS; ++j) { a[j] = -expf(ap[j]); h[j] = 0.f; }
    const float* __restrict__ wp = dtw + ((size_t)s * NDI + d) * NDR;
    #pragma unroll
    for (int r = 0; r < NDR; ++r) wdt[r] = wp[r];
    const float bias = dtb[s * NDI + d];
    const float Dd = Dp[s * NDI + d];

    const float* __restrict__ up = xc + ((size_t)(m * NB + b)) * NN * NDI + d;
    float* __restrict__ yp = y6 + ((size_t)(s * NB + b)) * NN * NDI + d;

    __syncthreads();

    for (int t = 0; t < NN; ++t) {
        const float* __restrict__ row = &xdl[t * 64];
        float dl = bias;
        #pragma unroll
        for (int r = 0; r < NDR; ++r) dl = fmaf(row[r], wdt[r], dl);
        const float delta = softplusf(dl);
        const int nsrc = rev ? (NN - 1 - t) : t;
        const float u = up[(size_t)nsrc * NDI];
        const float du = delta * u;
        float y = 0.f;
        #pragma unroll
        for (int j = 0; j < NDS; ++j) {
            const float dA = expf(delta * a[j]);
            h[j] = fmaf(dA, h[j], du * row[32 + j]);
            y = fmaf(h[j], row[48 + j], y);
        }
        yp[(size_t)t * NDI] = y + u * Dd;
    }
}

// ---------------------------------------------------------------------------
// K5: LN + fwd/rev combine + SiLU(z) gating. z in bf16, yg out bf16.
// ---------------------------------------------------------------------------
__global__ __launch_bounds__(256) void k_combine(
    const float* __restrict__ y6, const __hip_bfloat16* __restrict__ zbf,
    const float* __restrict__ g, const float* __restrict__ be,
    __hip_bfloat16* __restrict__ yg)
{
    const int t = blockIdx.x, b = blockIdx.y, m = blockIdx.z;
    const int tid = threadIdx.x;
    const float* __restrict__ rowf = y6 + ((size_t)(m * NB + b) * NN + t) * NDI;
    const float* __restrict__ rowr =
        y6 + ((size_t)((m + 3) * NB + b) * NN + (NN - 1 - t)) * NDI;
    const __hip_bfloat16* __restrict__ zrow =
        zbf + ((size_t)(m * NB + b) * NN + t) * NDI;

    float vf[4], vr2[4];
    float sf = 0.f, qf = 0.f, sr = 0.f, qr = 0.f;
    #pragma unroll
    for (int q = 0; q < 4; ++q) {
        const int dd = (q << 8) + tid;
        vf[q] = rowf[dd]; vr2[q] = rowr[dd];
        sf += vf[q]; qf = fmaf(vf[q], vf[q], qf);
        sr += vr2[q]; qr = fmaf(vr2[q], vr2[q], qr);
    }
    #pragma unroll
    for (int off = 32; off > 0; off >>= 1) {
        sf += __shfl_down(sf, off, 64);
        qf += __shfl_down(qf, off, 64);
        sr += __shfl_down(sr, off, 64);
        qr += __shfl_down(qr, off, 64);
    }
    __shared__ float red[4][4];
    const int wv = tid >> 6;
    if ((tid & 63) == 0) { red[wv][0] = sf; red[wv][1] = qf; red[wv][2] = sr; red[wv][3] = qr; }
    __syncthreads();
    const float tsf = red[0][0] + red[1][0] + red[2][0] + red[3][0];
    const float tqf = red[0][1] + red[1][1] + red[2][1] + red[3][1];
    const float tsr = red[0][2] + red[1][2] + red[2][2] + red[3][2];
    const float tqr = red[0][3] + red[1][3] + red[2][3] + red[3][3];
    const float muf = tsf * (1.f / NDI);
    const float varf = tqf * (1.f / NDI) - muf * muf;
    const float rsf = rsqrtf(varf + 1e-5f);
    const float mur = tsr * (1.f / NDI);
    const float varr = tqr * (1.f / NDI) - mur * mur;
    const float rsr = rsqrtf(varr + 1e-5f);

    #pragma unroll
    for (int q = 0; q < 4; ++q) {
        const int dd = (q << 8) + tid;
        const float lf = (vf[q] - muf) * rsf * g[m * NDI + dd] + be[m * NDI + dd];
        const float lr2 = (vr2[q] - mur) * rsr * g[(m + 3) * NDI + dd] + be[(m + 3) * NDI + dd];
        const float z = __bfloat162float(zrow[dd]);
        const float sig = 1.f / (1.f + expf(-z));
        yg[((size_t)(m * NB + b) * NN + t) * NDI + dd] =
            __float2bfloat16((lf + lr2) * z * sig);
    }
}

// ---------------------------------------------------------------------------
// K6: out_proj as bf16 MFMA GEMM + fp32 residual add.
// A: yg [12288][1024] bf16, B: wout [512][1024] bf16, C: out [12288][512] fp32.
// ---------------------------------------------------------------------------
__global__ __launch_bounds__(256) void k_gemm_outproj(
    const unsigned short* __restrict__ Abf,
    const unsigned short* __restrict__ Wbf,
    const float* __restrict__ rr, const float* __restrict__ nn,
    const float* __restrict__ tt, float* __restrict__ out)
{
    const int row0 = blockIdx.x * 128;   // over 12288
    const int col0 = blockIdx.y * 128;   // over 512
    const int K = 1024;
    const int NT = K / 32;

    const int tid = threadIdx.x;
    const int lane = tid & 63;
    const int wave = tid >> 6;
    const int wr = wave >> 1, wc = wave & 1;
    const int lr16 = lane & 15;
    const int kk8 = (lane >> 4) << 3;

    __shared__ __align__(16) short sA[2][128 * 32];
    __shared__ __align__(16) short sB[2][128 * 32];

    f32x4 acc[4][4];
    #pragma unroll
    for (int i = 0; i < 4; ++i)
        #pragma unroll
        for (int j = 0; j < 4; ++j)
            acc[i][j] = (f32x4){0.f, 0.f, 0.f, 0.f};

    #define STAGE(buf, t)                                                        \
        {                                                                        \
            const int k0 = (t) * 32;                                             \
            _Pragma("unroll")                                                    \
            for (int i = 0; i < 2; ++i) {                                        \
                const int c = i * 256 + tid;                                     \
                const int rowc = c >> 2;                                         \
                const int kc = (c & 3) << 3;                                     \
                gload16(Abf + (size_t)(row0 + rowc) * K + k0 + kc,               \
                        &sA[buf][rowc * 32 + kc]);                               \
                gload16(Wbf + (size_t)(col0 + rowc) * K + k0 + kc,               \
                        &sB[buf][rowc * 32 + kc]);                               \
            }                                                                    \
        }

    #define COMPUTE(buf)                                                         \
        {                                                                        \
            bf16x8 af[4], bfr[4];                                                \
            _Pragma("unroll")                                                    \
            for (int i = 0; i < 4; ++i) {                                        \
                af[i]  = *(const bf16x8*)&sA[buf][(wr * 64 + i * 16 + lr16) * 32 + kk8]; \
                bfr[i] = *(const bf16x8*)&sB[buf][(wc * 64 + i * 16 + lr16) * 32 + kk8]; \
            }                                                                    \
            _Pragma("unroll")                                                    \
            for (int i = 0; i < 4; ++i)                                          \
                _Pragma("unroll")                                                \
                for (int j = 0; j < 4; ++j)                                      \
                    acc[i][j] = __builtin_amdgcn_mfma_f32_16x16x32_bf16(         \
                        af[i], bfr[j], acc[i][j], 0, 0, 0);                      \
        }

    STAGE(0, 0);
    __syncthreads();
    int cur = 0;
    for (int t = 0; t < NT - 1; ++t) {
        STAGE(cur ^ 1, t + 1);
        COMPUTE(cur);
        __syncthreads();
        cur ^= 1;
    }
    COMPUTE(cur);

    const int m = row0 >> 12;  // uniform per block (128 | 4096)
    const float* __restrict__ resid = (m == 0) ? rr : (m == 1) ? nn : tt;
    #pragma unroll
    for (int i = 0; i < 4; ++i) {
        const int rb = row0 + wr * 64 + i * 16 + ((lane >> 4) << 2);
        #pragma unroll
        for (int j = 0; j < 4; ++j) {
            const int cc = col0 + wc * 64 + j * 16 + lr16;
            #pragma unroll
            for (int r = 0; r < 4; ++r) {
                const int row = rb + r;
                const int bt = row & 4095;
                out[(size_t)row * ND + cc] =
                    acc[i][j][r] + resid[(size_t)bt * ND + cc];
            }
        }
    }
    #undef STAGE
    #undef COMPUTE
}

// ---------------------------------------------------------------------------
extern "C" void kernel_launch(void* const* d_in, const int* in_sizes, int n_in,
                              void* d_out, int out_size, void* d_ws, size_t ws_size,
                              hipStream_t stream) {
    const float* rr   = (const float*)d_in[0];
    const float* nn   = (const float*)d_in[1];
    const float* tt   = (const float*)d_in[2];
    const float* wip  = (const float*)d_in[3];   // (3,2048,512)
    const float* cw   = (const float*)d_in[4];   // (3,1024,1,3,3)
    const float* cb   = (const float*)d_in[5];
    const float* gm   = (const float*)d_in[6];
    const float* bt   = (const float*)d_in[7];
    const float* mn   = (const float*)d_in[8];
    const float* vr   = (const float*)d_in[9];
    const float* xw   = (const float*)d_in[10];  // (6,64,1024)
    const float* dtw  = (const float*)d_in[11];  // (6,1024,32)
    const float* dtb  = (const float*)d_in[12];
    const float* alog = (const float*)d_in[13];  // (6,1024,16)
    const float* Dp   = (const float*)d_in[14];
    const float* lng  = (const float*)d_in[15];
    const float* lnb  = (const float*)d_in[16];
    const float* wout = (const float*)d_in[17];  // (512,1024)
    float* out = (float*)d_out;

    // workspace layout (bytes), total ~241 MiB
    uint8_t* p = (uint8_t*)d_ws;
    unsigned short* Abf    = (unsigned short*)p;          p += (size_t)3 * 4096 * 512 * 2;   // 12.6 MB
    unsigned short* Wbf    = (unsigned short*)p;          p += (size_t)3 * 2048 * 512 * 2;   //  6.3 MB
    unsigned short* Woutbf = (unsigned short*)p;          p += (size_t)512 * 1024 * 2;       //  1.0 MB
    float*          xb     = (float*)p;                   p += (size_t)3 * 4096 * 1024 * 4;  // 50.3 MB
    __hip_bfloat16* zbf    = (__hip_bfloat16*)p;          p += (size_t)3 * 4096 * 1024 * 2;  // 25.2 MB
    float*          xc     = (float*)p;                   p += (size_t)3 * 4096 * 1024 * 4;  // 50.3 MB
    float*          xdb    = (float*)p;                   p += (size_t)6 * 4096 * 64 * 4;    //  6.3 MB
    float*          y6     = (float*)p;                   p += (size_t)6 * 4096 * 1024 * 4;  // 100.7 MB
    __hip_bfloat16* ygbf   = (__hip_bfloat16*)xb;         // reuse xb (dead after conv)

    // bf16 conversions
    k_cvt<<<dim3(2048), 256, 0, stream>>>(rr,   Abf + (size_t)0 * 4096 * 512, 4096 * 512 / 4);
    k_cvt<<<dim3(2048), 256, 0, stream>>>(nn,   Abf + (size_t)1 * 4096 * 512, 4096 * 512 / 4);
    k_cvt<<<dim3(2048), 256, 0, stream>>>(tt,   Abf + (size_t)2 * 4096 * 512, 4096 * 512 / 4);
    k_cvt<<<dim3(2048), 256, 0, stream>>>(wip,  Wbf, 3 * 2048 * 512 / 4);
    k_cvt<<<dim3(512),  256, 0, stream>>>(wout, Woutbf, 512 * 1024 / 4);

    k_gemm_inproj<<<dim3(32, 16, 3), 256, 0, stream>>>(Abf, Wbf, xb, zbf);
    k_conv<<<dim3(128, 32, 3), 256, 0, stream>>>(xb, cw, cb, gm, bt, mn, vr, xc);
    k_xproj<<<dim3(64, 1, 6), 256, 0, stream>>>(xc, xw, xdb);
    k_scan<<<dim3(4, 32, 6), 256, 0, stream>>>(xc, xdb, dtw, dtb, alog, Dp, y6);
    k_combine<<<dim3(128, 32, 3), 256, 0, stream>>>(y6, zbf, lng, lnb, ygbf);
    k_gemm_outproj<<<dim3(96, 4, 1), 256, 0, stream>>>(
        (const unsigned short*)ygbf, Woutbf, rr, nn, tt, out);
}

// Round 4
// 590.393 us; speedup vs baseline: 1.1924x; 1.1924x over previous
//
#include <hip/hip_runtime.h>
#include <hip/hip_bf16.h>
#include <math.h>

// Problem constants
#define NB 32     // batch
#define NN 128    // sequence (= 16 x 8)
#define ND 512    // model dim
#define NDI 1024  // inner dim
#define NDS 16    // state dim
#define NDR 32    // dt rank

typedef __attribute__((ext_vector_type(8))) __bf16 bf16x8;
typedef __attribute__((ext_vector_type(4))) float f32x4;

typedef __attribute__((address_space(3))) void lds_void;
typedef const __attribute__((address_space(1))) void glob_void;

__device__ __forceinline__ void gload16(const void* g, void* l) {
    __builtin_amdgcn_global_load_lds((glob_void*)g, (lds_void*)l, 16, 0, 0);
}

__device__ __forceinline__ unsigned short f2bf(float x) {
    __hip_bfloat16 h = __float2bfloat16(x);
    return *(unsigned short*)&h;
}

// ---------------------------------------------------------------------------
// K0: fp32 -> bf16 conversion (RTNE). k_cvt3 handles r,n,t in one launch.
// ---------------------------------------------------------------------------
__global__ __launch_bounds__(256) void k_cvt(
    const float* __restrict__ s, unsigned short* __restrict__ d, int n4)
{
    for (int i = blockIdx.x * 256 + threadIdx.x; i < n4; i += gridDim.x * 256) {
        const float4 v = ((const float4*)s)[i];
        ushort4 o;
        o.x = f2bf(v.x); o.y = f2bf(v.y); o.z = f2bf(v.z); o.w = f2bf(v.w);
        ((ushort4*)d)[i] = o;
    }
}

__global__ __launch_bounds__(256) void k_cvt3(
    const float* __restrict__ rr, const float* __restrict__ nn,
    const float* __restrict__ tt, unsigned short* __restrict__ d, int n4)
{
    const int z = blockIdx.z;
    const float* __restrict__ s = (z == 0) ? rr : (z == 1) ? nn : tt;
    unsigned short* __restrict__ dz = d + (size_t)z * n4 * 4;
    for (int i = blockIdx.x * 256 + threadIdx.x; i < n4; i += gridDim.x * 256) {
        const float4 v = ((const float4*)s)[i];
        ushort4 o;
        o.x = f2bf(v.x); o.y = f2bf(v.y); o.z = f2bf(v.z); o.w = f2bf(v.w);
        ((ushort4*)dz)[i] = o;
    }
}

// ---------------------------------------------------------------------------
// K1: in_proj as bf16 MFMA GEMM (m97 structure). Tile 128x128, BK=32.
// ---------------------------------------------------------------------------
__global__ __launch_bounds__(256) void k_gemm_inproj(
    const unsigned short* __restrict__ Abf,
    const unsigned short* __restrict__ Wbf,
    float* __restrict__ xb, __hip_bfloat16* __restrict__ zbf)
{
    const int m = blockIdx.z;
    const int row0 = blockIdx.x * 128;
    const int col0 = blockIdx.y * 128;
    const unsigned short* __restrict__ A = Abf + (size_t)m * 4096 * 512;
    const unsigned short* __restrict__ Bw = Wbf + (size_t)m * 2048 * 512;
    const int K = 512;
    const int NT = K / 32;

    const int tid = threadIdx.x;
    const int lane = tid & 63;
    const int wave = tid >> 6;
    const int wr = wave >> 1, wc = wave & 1;
    const int lr16 = lane & 15;
    const int kk8 = (lane >> 4) << 3;

    __shared__ __align__(16) short sA[2][128 * 32];
    __shared__ __align__(16) short sB[2][128 * 32];

    f32x4 acc[4][4];
    #pragma unroll
    for (int i = 0; i < 4; ++i)
        #pragma unroll
        for (int j = 0; j < 4; ++j)
            acc[i][j] = (f32x4){0.f, 0.f, 0.f, 0.f};

    #define STAGE(buf, t)                                                        \
        {                                                                        \
            const int k0 = (t) * 32;                                             \
            _Pragma("unroll")                                                    \
            for (int i = 0; i < 2; ++i) {                                        \
                const int c = i * 256 + tid;                                     \
                const int rowc = c >> 2;                                         \
                const int kc = (c & 3) << 3;                                     \
                gload16(A + (size_t)(row0 + rowc) * K + k0 + kc,                 \
                        &sA[buf][rowc * 32 + kc]);                               \
                gload16(Bw + (size_t)(col0 + rowc) * K + k0 + kc,                \
                        &sB[buf][rowc * 32 + kc]);                               \
            }                                                                    \
        }

    #define COMPUTE(buf)                                                         \
        {                                                                        \
            bf16x8 af[4], bfr[4];                                                \
            _Pragma("unroll")                                                    \
            for (int i = 0; i < 4; ++i) {                                        \
                af[i]  = *(const bf16x8*)&sA[buf][(wr * 64 + i * 16 + lr16) * 32 + kk8]; \
                bfr[i] = *(const bf16x8*)&sB[buf][(wc * 64 + i * 16 + lr16) * 32 + kk8]; \
            }                                                                    \
            _Pragma("unroll")                                                    \
            for (int i = 0; i < 4; ++i)                                          \
                _Pragma("unroll")                                                \
                for (int j = 0; j < 4; ++j)                                      \
                    acc[i][j] = __builtin_amdgcn_mfma_f32_16x16x32_bf16(         \
                        af[i], bfr[j], acc[i][j], 0, 0, 0);                      \
        }

    STAGE(0, 0);
    __syncthreads();
    int cur = 0;
    for (int t = 0; t < NT - 1; ++t) {
        STAGE(cur ^ 1, t + 1);
        COMPUTE(cur);
        __syncthreads();
        cur ^= 1;
    }
    COMPUTE(cur);

    const bool isX = (col0 < 1024);
    #pragma unroll
    for (int i = 0; i < 4; ++i) {
        const int rb = row0 + wr * 64 + i * 16 + ((lane >> 4) << 2);
        #pragma unroll
        for (int j = 0; j < 4; ++j) {
            const int cc = col0 + wc * 64 + j * 16 + lr16;
            #pragma unroll
            for (int r = 0; r < 4; ++r) {
                const float v = acc[i][j][r];
                const int row = rb + r;
                if (isX)
                    xb[((size_t)m * 4096 + row) * 1024 + cc] = v;
                else
                    zbf[((size_t)m * 4096 + row) * 1024 + (cc - 1024)] =
                        __float2bfloat16(v);
            }
        }
    }
    #undef STAGE
    #undef COMPUTE
}

// ---------------------------------------------------------------------------
// K2: depthwise 3x3 conv (SAME) + bias + BN + SiLU. Spatial 16x8, n = h*8+w.
// ---------------------------------------------------------------------------
__global__ __launch_bounds__(256) void k_conv(
    const float* __restrict__ x, const float* __restrict__ cw,
    const float* __restrict__ cb, const float* __restrict__ gm,
    const float* __restrict__ bt, const float* __restrict__ mn,
    const float* __restrict__ vr, float* __restrict__ out)
{
    const int nIdx = blockIdx.x;       // 0..127
    const int b = blockIdx.y;
    const int m = blockIdx.z;
    const int h = nIdx >> 3, w = nIdx & 7;
    const float* __restrict__ xm = x + ((size_t)(m * NB + b)) * NN * NDI;

    #pragma unroll
    for (int q = 0; q < 4; ++q) {
        const int di = (q << 8) + threadIdx.x;
        const float* __restrict__ wp = cw + ((size_t)(m * NDI + di)) * 9;
        float s = 0.f;
        #pragma unroll
        for (int kh = 0; kh < 3; ++kh) {
            const int hh = h + kh - 1;
            if ((unsigned)hh < 16u) {
                #pragma unroll
                for (int kw = 0; kw < 3; ++kw) {
                    const int ww = w + kw - 1;
                    if ((unsigned)ww < 8u)
                        s = fmaf(xm[(size_t)(hh * 8 + ww) * NDI + di],
                                 wp[kh * 3 + kw], s);
                }
            }
        }
        const int c = m * NDI + di;
        const float scale = gm[c] * rsqrtf(vr[c] + 1e-5f);
        const float y = (s + cb[c] - mn[c]) * scale + bt[c];
        out[((size_t)(m * NB + b) * NN + nIdx) * NDI + di] = y / (1.f + __expf(-y));
    }
}

// ---------------------------------------------------------------------------
// K3: xproj (fp32 vector GEMM). xd[s,row,e], e in [0,64).
// ---------------------------------------------------------------------------
__global__ __launch_bounds__(256) void k_xproj(
    const float* __restrict__ xc, const float* __restrict__ xw,
    float* __restrict__ xd)
{
    const int s = blockIdx.z;
    const int m = s % 3;
    const bool rev = s >= 3;
    const float* __restrict__ A = xc + (size_t)m * 4096 * NDI;
    const float* __restrict__ Bw = xw + (size_t)s * 64 * NDI;
    const int row0 = blockIdx.x * 64;
    const int tid = threadIdx.x;
    const int tx = tid & 15, ty = tid >> 4;
    const int lr = tid >> 2;
    const int lk = (tid & 3) << 2;

    __shared__ float As[16][64];
    __shared__ float Bs[16][64];
    float acc[4][4] = {};

    const int arow = row0 + lr;
    const int ab = arow >> 7, at = arow & 127;
    const int srow = ab * NN + (rev ? (NN - 1 - at) : at);

    for (int k0 = 0; k0 < NDI; k0 += 16) {
        const float4 av = *(const float4*)(A + (size_t)srow * NDI + k0 + lk);
        const float4 bv = *(const float4*)(Bw + (size_t)lr * NDI + k0 + lk);
        __syncthreads();
        As[lk + 0][lr] = av.x; As[lk + 1][lr] = av.y;
        As[lk + 2][lr] = av.z; As[lk + 3][lr] = av.w;
        Bs[lk + 0][lr] = bv.x; Bs[lk + 1][lr] = bv.y;
        Bs[lk + 2][lr] = bv.z; Bs[lk + 3][lr] = bv.w;
        __syncthreads();
        #pragma unroll
        for (int kk = 0; kk < 16; ++kk) {
            const float4 a4 = *(const float4*)&As[kk][ty << 2];
            const float4 b4 = *(const float4*)&Bs[kk][tx << 2];
            const float ar[4] = {a4.x, a4.y, a4.z, a4.w};
            const float br[4] = {b4.x, b4.y, b4.z, b4.w};
            #pragma unroll
            for (int i = 0; i < 4; ++i)
                #pragma unroll
                for (int j = 0; j < 4; ++j)
                    acc[i][j] = fmaf(ar[i], br[j], acc[i][j]);
        }
    }
    const int e0 = tx << 2;
    #pragma unroll
    for (int i = 0; i < 4; ++i) {
        const int row = row0 + (ty << 2) + i;
        *(float4*)(xd + ((size_t)s * 4096 + row) * 64 + e0) =
            make_float4(acc[i][0], acc[i][1], acc[i][2], acc[i][3]);
    }
}

// ---------------------------------------------------------------------------
// K4: fused selective scan, v3. One thread per (s,b,d); 128 steps.
// xd row is wave-uniform (address from blockIdx only). dt rows consumed
// before B/C rows load (low register liveness). exp2-based transcendentals:
// dA = exp2f(delta * a2[j]) with a2 = -exp(A_log)*log2(e).
// ---------------------------------------------------------------------------
__global__ __launch_bounds__(256) void k_scan(
    const float* __restrict__ xc, const float* __restrict__ xd,
    const float* __restrict__ dtw, const float* __restrict__ dtb,
    const float* __restrict__ alog, const float* __restrict__ Dp,
    float* __restrict__ y6)
{
    const int s = blockIdx.z, b = blockIdx.y;
    const int d = blockIdx.x * 256 + threadIdx.x;
    const int m = (s >= 3) ? (s - 3) : s;
    const bool rev = s >= 3;
    const float L2E = 1.442695040888963f;

    float a2[NDS], h[NDS], wdt[NDR];
    const float* __restrict__ ap = alog + ((size_t)s * NDI + d) * NDS;
    #pragma unroll
    for (int j = 0; j < NDS; j += 4) {
        const float4 v = *(const float4*)(ap + j);
        a2[j]     = -__expf(v.x) * L2E;
        a2[j + 1] = -__expf(v.y) * L2E;
        a2[j + 2] = -__expf(v.z) * L2E;
        a2[j + 3] = -__expf(v.w) * L2E;
        h[j] = h[j + 1] = h[j + 2] = h[j + 3] = 0.f;
    }
    const float* __restrict__ wp = dtw + ((size_t)s * NDI + d) * NDR;
    #pragma unroll
    for (int r = 0; r < NDR; r += 4)
        *(float4*)&wdt[r] = *(const float4*)(wp + r);
    const float bias = dtb[s * NDI + d];
    const float Dd = Dp[s * NDI + d];

    const float* __restrict__ up = xc + ((size_t)(m * NB + b)) * NN * NDI + d;
    const float* __restrict__ xrow = xd + ((size_t)(s * NB + b)) * NN * 64;
    float* __restrict__ yp = y6 + ((size_t)(s * NB + b)) * NN * NDI + d;

    float u = up[(size_t)(rev ? (NN - 1) : 0) * NDI];

    for (int t = 0; t < NN; ++t) {
        const float* __restrict__ xr = xrow + (size_t)t * 64;  // uniform addr

        // dt-projection: load 8 x float4, consume immediately into dl
        float dl = bias;
        #pragma unroll
        for (int q = 0; q < 8; ++q) {
            const float4 v = *(const float4*)(xr + q * 4);
            dl = fmaf(v.x, wdt[q * 4 + 0], dl);
            dl = fmaf(v.y, wdt[q * 4 + 1], dl);
            dl = fmaf(v.z, wdt[q * 4 + 2], dl);
            dl = fmaf(v.w, wdt[q * 4 + 3], dl);
        }

        // prefetch next u
        float u_n = 0.f;
        if (t + 1 < NN) {
            const int ns = rev ? (NN - 2 - t) : (t + 1);
            u_n = up[(size_t)ns * NDI];
        }

        // stable softplus via exp2/log2
        const float e = exp2f(-fabsf(dl) * L2E);
        const float delta = fmaxf(dl, 0.f) + __logf(1.f + e);
        const float du = delta * u;

        // state update: B rows (xr+32..47), C rows (xr+48..63)
        float4 Bv[4], Cv[4];
        #pragma unroll
        for (int q = 0; q < 4; ++q) Bv[q] = *(const float4*)(xr + 32 + q * 4);
        #pragma unroll
        for (int q = 0; q < 4; ++q) Cv[q] = *(const float4*)(xr + 48 + q * 4);

        float y = 0.f;
        #pragma unroll
        for (int j = 0; j < NDS; ++j) {
            const float dA = exp2f(delta * a2[j]);
            const float Bj = ((const float*)Bv)[j];
            const float Cj = ((const float*)Cv)[j];
            h[j] = fmaf(dA, h[j], du * Bj);
            y = fmaf(h[j], Cj, y);
        }
        yp[(size_t)t * NDI] = fmaf(u, Dd, y);
        u = u_n;
    }
}

// ---------------------------------------------------------------------------
// K5: LN + fwd/rev combine + SiLU(z) gating, float4-vectorized.
// One block per (m,b,t); each thread owns 4 consecutive channels.
// ---------------------------------------------------------------------------
__global__ __launch_bounds__(256) void k_combine(
    const float* __restrict__ y6, const __hip_bfloat16* __restrict__ zbf,
    const float* __restrict__ g, const float* __restrict__ be,
    __hip_bfloat16* __restrict__ yg)
{
    const int t = blockIdx.x, b = blockIdx.y, m = blockIdx.z;
    const int tid = threadIdx.x;
    const int dd = tid << 2;
    const float* __restrict__ rowf = y6 + ((size_t)(m * NB + b) * NN + t) * NDI;
    const float* __restrict__ rowr =
        y6 + ((size_t)((m + 3) * NB + b) * NN + (NN - 1 - t)) * NDI;
    const __hip_bfloat16* __restrict__ zrow =
        zbf + ((size_t)(m * NB + b) * NN + t) * NDI;

    const float4 vf = *(const float4*)(rowf + dd);
    const float4 vr = *(const float4*)(rowr + dd);
    float sf = vf.x + vf.y + vf.z + vf.w;
    float qf = vf.x * vf.x + vf.y * vf.y + vf.z * vf.z + vf.w * vf.w;
    float sr = vr.x + vr.y + vr.z + vr.w;
    float qr = vr.x * vr.x + vr.y * vr.y + vr.z * vr.z + vr.w * vr.w;

    #pragma unroll
    for (int off = 32; off > 0; off >>= 1) {
        sf += __shfl_down(sf, off, 64);
        qf += __shfl_down(qf, off, 64);
        sr += __shfl_down(sr, off, 64);
        qr += __shfl_down(qr, off, 64);
    }
    __shared__ float red[4][4];
    const int wv = tid >> 6;
    if ((tid & 63) == 0) { red[wv][0] = sf; red[wv][1] = qf; red[wv][2] = sr; red[wv][3] = qr; }
    __syncthreads();
    const float tsf = red[0][0] + red[1][0] + red[2][0] + red[3][0];
    const float tqf = red[0][1] + red[1][1] + red[2][1] + red[3][1];
    const float tsr = red[0][2] + red[1][2] + red[2][2] + red[3][2];
    const float tqr = red[0][3] + red[1][3] + red[2][3] + red[3][3];
    const float muf = tsf * (1.f / NDI);
    const float varf = tqf * (1.f / NDI) - muf * muf;
    const float rsf = rsqrtf(varf + 1e-5f);
    const float mur = tsr * (1.f / NDI);
    const float varr = tqr * (1.f / NDI) - mur * mur;
    const float rsr = rsqrtf(varr + 1e-5f);

    const float4 gf = *(const float4*)(g + m * NDI + dd);
    const float4 bf = *(const float4*)(be + m * NDI + dd);
    const float4 gr = *(const float4*)(g + (m + 3) * NDI + dd);
    const float4 br = *(const float4*)(be + (m + 3) * NDI + dd);
    const ushort4 zu = *(const ushort4*)(zrow + dd);

    float lf[4], lr2[4], zv[4];
    lf[0] = (vf.x - muf) * rsf * gf.x + bf.x;
    lf[1] = (vf.y - muf) * rsf * gf.y + bf.y;
    lf[2] = (vf.z - muf) * rsf * gf.z + bf.z;
    lf[3] = (vf.w - muf) * rsf * gf.w + bf.w;
    lr2[0] = (vr.x - mur) * rsr * gr.x + br.x;
    lr2[1] = (vr.y - mur) * rsr * gr.y + br.y;
    lr2[2] = (vr.z - mur) * rsr * gr.z + br.z;
    lr2[3] = (vr.w - mur) * rsr * gr.w + br.w;
    zv[0] = __bfloat162float(*(const __hip_bfloat16*)&zu.x);
    zv[1] = __bfloat162float(*(const __hip_bfloat16*)&zu.y);
    zv[2] = __bfloat162float(*(const __hip_bfloat16*)&zu.z);
    zv[3] = __bfloat162float(*(const __hip_bfloat16*)&zu.w);

    ushort4 o;
    unsigned short* op = (unsigned short*)&o;
    #pragma unroll
    for (int q = 0; q < 4; ++q) {
        const float sig = 1.f / (1.f + __expf(-zv[q]));
        op[q] = f2bf((lf[q] + lr2[q]) * zv[q] * sig);
    }
    *(ushort4*)(yg + ((size_t)(m * NB + b) * NN + t) * NDI + dd) = o;
}

// ---------------------------------------------------------------------------
// K6: out_proj as bf16 MFMA GEMM + fp32 residual add.
// ---------------------------------------------------------------------------
__global__ __launch_bounds__(256) void k_gemm_outproj(
    const unsigned short* __restrict__ Abf,
    const unsigned short* __restrict__ Wbf,
    const float* __restrict__ rr, const float* __restrict__ nn,
    const float* __restrict__ tt, float* __restrict__ out)
{
    const int row0 = blockIdx.x * 128;   // over 12288
    const int col0 = blockIdx.y * 128;   // over 512
    const int K = 1024;
    const int NT = K / 32;

    const int tid = threadIdx.x;
    const int lane = tid & 63;
    const int wave = tid >> 6;
    const int wr = wave >> 1, wc = wave & 1;
    const int lr16 = lane & 15;
    const int kk8 = (lane >> 4) << 3;

    __shared__ __align__(16) short sA[2][128 * 32];
    __shared__ __align__(16) short sB[2][128 * 32];

    f32x4 acc[4][4];
    #pragma unroll
    for (int i = 0; i < 4; ++i)
        #pragma unroll
        for (int j = 0; j < 4; ++j)
            acc[i][j] = (f32x4){0.f, 0.f, 0.f, 0.f};

    #define STAGE(buf, t)                                                        \
        {                                                                        \
            const int k0 = (t) * 32;                                             \
            _Pragma("unroll")                                                    \
            for (int i = 0; i < 2; ++i) {                                        \
                const int c = i * 256 + tid;                                     \
                const int rowc = c >> 2;                                         \
                const int kc = (c & 3) << 3;                                     \
                gload16(Abf + (size_t)(row0 + rowc) * K + k0 + kc,               \
                        &sA[buf][rowc * 32 + kc]);                               \
                gload16(Wbf + (size_t)(col0 + rowc) * K + k0 + kc,               \
                        &sB[buf][rowc * 32 + kc]);                               \
            }                                                                    \
        }

    #define COMPUTE(buf)                                                         \
        {                                                                        \
            bf16x8 af[4], bfr[4];                                                \
            _Pragma("unroll")                                                    \
            for (int i = 0; i < 4; ++i) {                                        \
                af[i]  = *(const bf16x8*)&sA[buf][(wr * 64 + i * 16 + lr16) * 32 + kk8]; \
                bfr[i] = *(const bf16x8*)&sB[buf][(wc * 64 + i * 16 + lr16) * 32 + kk8]; \
            }                                                                    \
            _Pragma("unroll")                                                    \
            for (int i = 0; i < 4; ++i)                                          \
                _Pragma("unroll")                                                \
                for (int j = 0; j < 4; ++j)                                      \
                    acc[i][j] = __builtin_amdgcn_mfma_f32_16x16x32_bf16(         \
                        af[i], bfr[j], acc[i][j], 0, 0, 0);                      \
        }

    STAGE(0, 0);
    __syncthreads();
    int cur = 0;
    for (int t = 0; t < NT - 1; ++t) {
        STAGE(cur ^ 1, t + 1);
        COMPUTE(cur);
        __syncthreads();
        cur ^= 1;
    }
    COMPUTE(cur);

    const int m = row0 >> 12;  // uniform per block (128 | 4096)
    const float* __restrict__ resid = (m == 0) ? rr : (m == 1) ? nn : tt;
    #pragma unroll
    for (int i = 0; i < 4; ++i) {
        const int rb = row0 + wr * 64 + i * 16 + ((lane >> 4) << 2);
        #pragma unroll
        for (int j = 0; j < 4; ++j) {
            const int cc = col0 + wc * 64 + j * 16 + lr16;
            #pragma unroll
            for (int r = 0; r < 4; ++r) {
                const int row = rb + r;
                const int bt = row & 4095;
                out[(size_t)row * ND + cc] =
                    acc[i][j][r] + resid[(size_t)bt * ND + cc];
            }
        }
    }
    #undef STAGE
    #undef COMPUTE
}

// ---------------------------------------------------------------------------
extern "C" void kernel_launch(void* const* d_in, const int* in_sizes, int n_in,
                              void* d_out, int out_size, void* d_ws, size_t ws_size,
                              hipStream_t stream) {
    const float* rr   = (const float*)d_in[0];
    const float* nn   = (const float*)d_in[1];
    const float* tt   = (const float*)d_in[2];
    const float* wip  = (const float*)d_in[3];   // (3,2048,512)
    const float* cw   = (const float*)d_in[4];   // (3,1024,1,3,3)
    const float* cb   = (const float*)d_in[5];
    const float* gm   = (const float*)d_in[6];
    const float* bt   = (const float*)d_in[7];
    const float* mn   = (const float*)d_in[8];
    const float* vr   = (const float*)d_in[9];
    const float* xw   = (const float*)d_in[10];  // (6,64,1024)
    const float* dtw  = (const float*)d_in[11];  // (6,1024,32)
    const float* dtb  = (const float*)d_in[12];
    const float* alog = (const float*)d_in[13];  // (6,1024,16)
    const float* Dp   = (const float*)d_in[14];
    const float* lng  = (const float*)d_in[15];
    const float* lnb  = (const float*)d_in[16];
    const float* wout = (const float*)d_in[17];  // (512,1024)
    float* out = (float*)d_out;

    // workspace layout (bytes), total ~253 MiB
    uint8_t* p = (uint8_t*)d_ws;
    unsigned short* Abf    = (unsigned short*)p;          p += (size_t)3 * 4096 * 512 * 2;   // 12.6 MB
    unsigned short* Wbf    = (unsigned short*)p;          p += (size_t)3 * 2048 * 512 * 2;   //  6.3 MB
    unsigned short* Woutbf = (unsigned short*)p;          p += (size_t)512 * 1024 * 2;       //  1.0 MB
    float*          xb     = (float*)p;                   p += (size_t)3 * 4096 * 1024 * 4;  // 50.3 MB
    __hip_bfloat16* zbf    = (__hip_bfloat16*)p;          p += (size_t)3 * 4096 * 1024 * 2;  // 25.2 MB
    float*          xc     = (float*)p;                   p += (size_t)3 * 4096 * 1024 * 4;  // 50.3 MB
    float*          xdb    = (float*)p;                   p += (size_t)6 * 4096 * 64 * 4;    //  6.3 MB
    float*          y6     = (float*)p;                   p += (size_t)6 * 4096 * 1024 * 4;  // 100.7 MB
    __hip_bfloat16* ygbf   = (__hip_bfloat16*)xb;         // reuse xb (dead after conv)

    // bf16 conversions
    k_cvt3<<<dim3(2048, 1, 3), 256, 0, stream>>>(rr, nn, tt, Abf, 4096 * 512 / 4);
    k_cvt<<<dim3(2048), 256, 0, stream>>>(wip,  Wbf, 3 * 2048 * 512 / 4);
    k_cvt<<<dim3(512),  256, 0, stream>>>(wout, Woutbf, 512 * 1024 / 4);

    k_gemm_inproj<<<dim3(32, 16, 3), 256, 0, stream>>>(Abf, Wbf, xb, zbf);
    k_conv<<<dim3(128, 32, 3), 256, 0, stream>>>(xb, cw, cb, gm, bt, mn, vr, xc);
    k_xproj<<<dim3(64, 1, 6), 256, 0, stream>>>(xc, xw, xdb);
    k_scan<<<dim3(4, 32, 6), 256, 0, stream>>>(xc, xdb, dtw, dtb, alog, Dp, y6);
    k_combine<<<dim3(128, 32, 3), 256, 0, stream>>>(y6, zbf, lng, lnb, ygbf);
    k_gemm_outproj<<<dim3(96, 4, 1), 256, 0, stream>>>(
        (const unsigned short*)ygbf, Woutbf, rr, nn, tt, out);
}